// Round 12
// baseline (272.239 us; speedup 1.0000x reference)
//
#include <hip/hip_runtime.h>
#include <hip/hip_bf16.h>
#include <cstdint>

#define HDIM 256

typedef __attribute__((ext_vector_type(8))) short bf16x8;
typedef __attribute__((ext_vector_type(4))) float f32x4;
typedef __attribute__((ext_vector_type(4))) unsigned short u16x4;

__device__ __forceinline__ float bf2f(unsigned short u) {
    union { unsigned u; float f; } v; v.u = ((unsigned)u) << 16; return v.f;
}
__device__ __forceinline__ unsigned short f2bf(float f) {
    union { float f; unsigned u; } v; v.f = f;
    unsigned u = v.u;
    return (unsigned short)((u + 0x7fffu + ((u >> 16) & 1u)) >> 16);
}
__device__ __forceinline__ void gload_lds16(const void* g, void* l) {
    __builtin_amdgcn_global_load_lds((const __attribute__((address_space(1))) void*)g,
                                     (__attribute__((address_space(3))) void*)l, 16, 0, 0);
}
__device__ __forceinline__ float fsigm(float x) {
    return 1.f / (1.f + __expf(-x));
}
__device__ __forceinline__ float ftanh(float x) {
    float ax = fabsf(x);
    float z = __expf(2.f * ax);
    float th = 1.f - 2.f / (z + 1.f);
    return copysignf(th, x);
}

// ---- merged: iteration-0 mean/cast (blocks [0,B)) + weight/bias/offs prep (tail) ----
// nt loads on the f32 stream (read-once) and nt stores on the bf16 stream
// (write-once this kernel; attn re-reads it later — experiment: does skipping
// write-allocate free TCC bandwidth for the read stream?)
template<bool BF>
__global__ void __launch_bounds__(256) k_prep_mean(
        const float* __restrict__ nodes, const int* __restrict__ gid,
        const float* __restrict__ Wih0, const float* __restrict__ Whh0,
        const float* __restrict__ bih0, const float* __restrict__ bhh0,
        const float* __restrict__ Wih1, const float* __restrict__ Whh1,
        const float* __restrict__ bih1, const float* __restrict__ bhh1,
        unsigned short* __restrict__ W0, unsigned short* __restrict__ W1,
        float* __restrict__ b0, float* __restrict__ b1,
        int* __restrict__ offs,
        unsigned short* __restrict__ nbf, unsigned short* __restrict__ xr,
        unsigned short* __restrict__ xb1z,
        float* __restrict__ c0, float* __restrict__ c1, int N, int B) {
    int bid = blockIdx.x;
    int t = threadIdx.x;
    if (bid < B) {
        __shared__ float red[4 * HDIM];
        int g = bid;
        int lane = t & 63, wid = t >> 6;
        int lo = 0, hi = N;
        while (lo < hi) { int mid = (lo + hi) >> 1; if (gid[mid] < g) lo = mid + 1; else hi = mid; }
        int start = lo;
        hi = N;
        while (lo < hi) { int mid = (lo + hi) >> 1; if (gid[mid] < g + 1) lo = mid + 1; else hi = mid; }
        int end = lo;
        int Nm1 = N - 1;
        size_t col = (size_t)lane * 4;
        f32x4 acc = {0.f, 0.f, 0.f, 0.f};
        for (int vi0 = start + wid * 4; vi0 < end; vi0 += 16) {
            f32x4 v[4];
#pragma unroll
            for (int r = 0; r < 4; ++r)
                v[r] = __builtin_nontemporal_load(
                    (const f32x4*)(nodes + (size_t)min(vi0 + r, Nm1) * HDIM + col));
#pragma unroll
            for (int r = 0; r < 4; ++r) {
                if (vi0 + r < end) {      // wave-uniform
                    acc += v[r];
                    if (BF) {
                        u16x4 o;
                        o.x = f2bf(v[r].x); o.y = f2bf(v[r].y);
                        o.z = f2bf(v[r].z); o.w = f2bf(v[r].w);
                        __builtin_nontemporal_store(o,
                            (u16x4*)(nbf + (size_t)(vi0 + r) * HDIM + col));
                    }
                }
            }
        }
        *(f32x4*)(red + wid * HDIM + lane * 4) = acc;
        __syncthreads();
        int n = end - start;
        float r = red[t] + red[HDIM + t] + red[2 * HDIM + t] + red[3 * HDIM + t];
        r = (n > 0) ? r / (float)n : 0.f;
        xr[(size_t)g * 768 + t] = 0;                 // q block of step-0 xb0
        xr[(size_t)g * 768 + HDIM + t] = f2bf(r);    // r block
        xr[(size_t)g * 768 + 512 + t] = 0;           // h0 block
        xb1z[(size_t)g * 512 + 256 + t] = 0;         // h1prev block of step-0 xb1
        c0[(size_t)g * HDIM + t] = 0.f;
        c1[(size_t)g * HDIM + t] = 0.f;
        return;
    }
    int idx = (bid - B) * 256 + t;
    const int n0 = 1024 * 768, n1 = 1024 * 512;
    if (idx < n0) {
        int r = idx / 768, k = idx - r * 768;
        int orow = ((r >> 4) & 3) * 256 + ((r >> 6) << 4) + (r & 15);
        float v = (k < 512) ? Wih0[orow * 512 + k] : Whh0[orow * 256 + (k - 512)];
        W0[idx] = f2bf(v);
    } else if (idx < n0 + n1) {
        int j = idx - n0;
        int r = j >> 9, k = j & 511;
        int orow = ((r >> 4) & 3) * 256 + ((r >> 6) << 4) + (r & 15);
        float v = (k < 256) ? Wih1[orow * 256 + k] : Whh1[orow * 256 + (k - 256)];
        W1[j] = f2bf(v);
    } else if (idx < n0 + n1 + 1024) {
        int r = idx - (n0 + n1);
        int orow = ((r >> 4) & 3) * 256 + ((r >> 6) << 4) + (r & 15);
        b0[r] = bih0[orow] + bhh0[orow];
        b1[r] = bih1[orow] + bhh1[orow];
    } else if (idx <= n0 + n1 + 1024 + B) {
        int g = idx - (n0 + n1 + 1024);
        int lo = 0, hi = N;
        while (lo < hi) { int mid = (lo + hi) >> 1; if (gid[mid] < g) lo = mid + 1; else hi = mid; }
        offs[g] = lo;
    }
}

// ---- attention: single global read, register-online softmax, 2-deep prefetch ----
// wave handles 4 nodes/iter: half h -> rows vi0+h and vi0+2+h
template<bool LAST>
__global__ void __launch_bounds__(256) k_attn(const unsigned short* __restrict__ nb,
                                              const int* __restrict__ offs,
                                              const float* __restrict__ q,
                                              float* __restrict__ out,
                                              unsigned short* __restrict__ xr, int N) {
    __shared__ float qs[HDIM];
    __shared__ float redr[8 * HDIM];
    __shared__ float redm[8], redd[8];
    int g = blockIdx.x, t = threadIdx.x;
    int lane = t & 63, wid = t >> 6;
    int half = lane >> 5, hl = lane & 31;
    int start = offs[g], end = offs[g + 1];
    int Nm1 = N - 1;
    float qv = q[(size_t)g * HDIM + t];
    qs[t] = qv;
    __syncthreads();
    float qv8[8];
#pragma unroll
    for (int j = 0; j < 8; ++j) qv8[j] = qs[hl * 8 + j];
    float m = -INFINITY, d = 0.f, racc[8];
#pragma unroll
    for (int j = 0; j < 8; ++j) racc[j] = 0.f;
    size_t col = (size_t)hl * 8;
    int vi0 = start + wid * 4;
    bf16x8 cura = *(const bf16x8*)(nb + (size_t)min(vi0 + half, Nm1) * HDIM + col);
    bf16x8 curb = *(const bf16x8*)(nb + (size_t)min(vi0 + 2 + half, Nm1) * HDIM + col);
    for (; vi0 < end; vi0 += 16) {
        int nvi = vi0 + 16;
        bf16x8 nxta = *(const bf16x8*)(nb + (size_t)min(nvi + half, Nm1) * HDIM + col);
        bf16x8 nxtb = *(const bf16x8*)(nb + (size_t)min(nvi + 2 + half, Nm1) * HDIM + col);
        int a = vi0 + half, b = a + 2;
        if (a < end) {                 // uniform per 32-lane half
            float xa[8], xb[8];
#pragma unroll
            for (int j = 0; j < 8; ++j) {
                xa[j] = bf2f((unsigned short)cura[j]);
                xb[j] = bf2f((unsigned short)curb[j]);
            }
            float ea = 0.f, eb = 0.f;
#pragma unroll
            for (int j = 0; j < 8; ++j) {
                ea = fmaf(qv8[j], xa[j], ea);
                eb = fmaf(qv8[j], xb[j], eb);
            }
#pragma unroll
            for (int o = 16; o >= 1; o >>= 1) {
                ea += __shfl_xor(ea, o, 64);
                eb += __shfl_xor(eb, o, 64);
            }
            if (b >= end) eb = -INFINITY;
            float nm = fmaxf(fmaxf(m, ea), eb);
            float sc = __expf(m - nm);
            float wa = __expf(ea - nm);
            float wb = __expf(eb - nm);
            m = nm;
            d = fmaf(d, sc, wa + wb);
#pragma unroll
            for (int j = 0; j < 8; ++j)
                racc[j] = fmaf(racc[j], sc, fmaf(wa, xa[j], wb * xb[j]));
        }
        cura = nxta; curb = nxtb;
    }
    int g2 = wid * 2 + half;
    *(float4*)(redr + g2 * HDIM + hl * 8)     = (float4){racc[0], racc[1], racc[2], racc[3]};
    *(float4*)(redr + g2 * HDIM + hl * 8 + 4) = (float4){racc[4], racc[5], racc[6], racc[7]};
    if (hl == 0) { redm[g2] = m; redd[g2] = d; }
    __syncthreads();
    float M = -INFINITY;
#pragma unroll
    for (int i = 0; i < 8; ++i) M = fmaxf(M, redm[i]);
    float D = 0.f, R = 0.f;
#pragma unroll
    for (int i = 0; i < 8; ++i) {
        float s = (redm[i] == -INFINITY) ? 0.f : __expf(redm[i] - M);
        D += redd[i] * s;
        R += redr[i * HDIM + t] * s;
    }
    float r = (D > 0.f) ? R / D : 0.f;
    if (LAST) {
        size_t ob = (size_t)g * (2 * HDIM);
        out[ob + t] = qv;
        out[ob + HDIM + t] = r;
    } else {
        xr[(size_t)g * 768 + HDIM + t] = f2bf(r);
    }
}

// ---- f32 fallback attention (no bf16 workspace) ----
template<bool LAST>
__global__ void __launch_bounds__(256) k_attn_f32(const float* __restrict__ nf,
                                                  const int* __restrict__ offs,
                                                  const float* __restrict__ q,
                                                  float* __restrict__ out,
                                                  unsigned short* __restrict__ xr) {
    __shared__ float qs[HDIM];
    __shared__ float redr[4 * HDIM];
    __shared__ float redm[4], redd[4];
    int g = blockIdx.x, t = threadIdx.x;
    int lane = t & 63, wid = t >> 6;
    int start = offs[g], end = offs[g + 1];
    float qv = q[(size_t)g * HDIM + t];
    qs[t] = qv;
    __syncthreads();
    float4 qq = *(const float4*)(qs + lane * 4);
    float m = -INFINITY, d = 0.f;
    float4 racc = {0.f, 0.f, 0.f, 0.f};
    for (int vi = start + wid; vi < end; vi += 4) {
        float4 x = *(const float4*)(nf + (size_t)vi * HDIM + lane * 4);
        float e = qq.x * x.x + qq.y * x.y + qq.z * x.z + qq.w * x.w;
#pragma unroll
        for (int o = 32; o >= 1; o >>= 1) e += __shfl_xor(e, o, 64);
        float nm = fmaxf(m, e);
        float sc = __expf(m - nm);
        float wv = __expf(e - nm);
        m = nm;
        d = d * sc + wv;
        racc.x = racc.x * sc + wv * x.x;
        racc.y = racc.y * sc + wv * x.y;
        racc.z = racc.z * sc + wv * x.z;
        racc.w = racc.w * sc + wv * x.w;
    }
    *(float4*)(redr + wid * HDIM + lane * 4) = racc;
    if (lane == 0) { redm[wid] = m; redd[wid] = d; }
    __syncthreads();
    float M = fmaxf(fmaxf(redm[0], redm[1]), fmaxf(redm[2], redm[3]));
    float D = 0.f, R = 0.f;
#pragma unroll
    for (int i = 0; i < 4; ++i) {
        float s = (redm[i] == -INFINITY) ? 0.f : __expf(redm[i] - M);
        D += redd[i] * s;
        R += redr[i * HDIM + t] * s;
    }
    float r = (D > 0.f) ? R / D : 0.f;
    if (LAST) {
        size_t ob = (size_t)g * (2 * HDIM);
        out[ob + t] = qv;
        out[ob + HDIM + t] = r;
    } else {
        xr[(size_t)g * 768 + HDIM + t] = f2bf(r);
    }
}

// ---- bf16 MFMA GEMM (64x128 tile, 4 waves), BK=64, 3-buffer pipelined LDS
//      (prefetch distance 2, counted vmcnt, raw barriers), XOR chunk swizzle,
//      fused LSTM-cell epilogue. Gate-interleaved W layout (see k_prep_mean). ----
template<int K, int PHASE>
__global__ void __launch_bounds__(256) k_gemm_lstm(const unsigned short* __restrict__ A,
                                                   const unsigned short* __restrict__ W,
                                                   const float* __restrict__ bias_p,
                                                   float* __restrict__ c,
                                                   unsigned short* __restrict__ xa,
                                                   unsigned short* __restrict__ xb,
                                                   float* __restrict__ qout) {
    constexpr int BK = 64;
    constexpr int NT = K / BK;           // 12 (K=768) or 8 (K=512)
    __shared__ unsigned short lA[3 * 64 * BK];    // 24 KB
    __shared__ unsigned short lB[3 * 128 * BK];   // 48 KB
    int t = threadIdx.x, lane = t & 63, wid = t >> 6;
    int wy = wid >> 1, wx = wid & 1;
    int brow = blockIdx.x * 64, bcol = blockIdx.y * 128;
    f32x4 acc[2][4];
#pragma unroll
    for (int i = 0; i < 2; ++i)
#pragma unroll
        for (int j = 0; j < 4; ++j) acc[i][j] = (f32x4){0.f, 0.f, 0.f, 0.f};
    const unsigned short* gA = A + (size_t)brow * K;
    const unsigned short* gW = W + (size_t)bcol * K;
    auto stage = [&](int tt, int b) {
        int k0 = tt * BK;
        unsigned short* dA = lA + b * (64 * BK);
        unsigned short* dB = lB + b * (128 * BK);
#pragma unroll
        for (int r = 0; r < 2; ++r) {
            int u = t + r * 256;
            int row = u >> 3, sc8 = (u & 7) ^ (row & 7);
            gload_lds16(gA + (size_t)row * K + k0 + sc8 * 8, dA + u * 8);
        }
#pragma unroll
        for (int r = 0; r < 4; ++r) {
            int u = t + r * 256;
            int row = u >> 3, sc8 = (u & 7) ^ (row & 7);
            gload_lds16(gW + (size_t)row * K + k0 + sc8 * 8, dB + u * 8);
        }
    };
    stage(0, 0);
    stage(1, 1);
    asm volatile("s_waitcnt vmcnt(6)" ::: "memory");   // tile 0 landed (own wave)
    __builtin_amdgcn_s_barrier();                       // -> landed for all waves
    int arow = wy * 32 + (lane & 15);
    int brow2 = wx * 64 + (lane & 15);
    int gc8 = lane >> 4;                                // col-chunk base (kh adds 4)
#pragma unroll
    for (int tt = 0; tt < NT; ++tt) {
        const unsigned short* bA = lA + (tt % 3) * (64 * BK);
        const unsigned short* bB = lB + (tt % 3) * (128 * BK);
        bf16x8 af[2][2], bfr[2][4];
#pragma unroll
        for (int kh = 0; kh < 2; ++kh) {
#pragma unroll
            for (int mm = 0; mm < 2; ++mm) {
                int row = arow + mm * 16;
                int ch = (gc8 + kh * 4) ^ (row & 7);
                af[kh][mm] = *(const bf16x8*)(bA + row * BK + ch * 8);
            }
#pragma unroll
            for (int nn = 0; nn < 4; ++nn) {
                int row = brow2 + nn * 16;
                int ch = (gc8 + kh * 4) ^ (row & 7);
                bfr[kh][nn] = *(const bf16x8*)(bB + row * BK + ch * 8);
            }
        }
        if (tt + 2 < NT) stage(tt + 2, (tt + 2) % 3);   // flies under MFMA + next stall
#pragma unroll
        for (int kh = 0; kh < 2; ++kh)
#pragma unroll
            for (int mm = 0; mm < 2; ++mm)
#pragma unroll
                for (int nn = 0; nn < 4; ++nn)
                    acc[mm][nn] = __builtin_amdgcn_mfma_f32_16x16x32_bf16(
                        af[kh][mm], bfr[kh][nn], acc[mm][nn], 0, 0, 0);
        if (tt + 1 < NT) {
            if (tt + 2 < NT) asm volatile("s_waitcnt vmcnt(6)" ::: "memory");
            else             asm volatile("s_waitcnt vmcnt(0)" ::: "memory");
            __builtin_amdgcn_s_barrier();
        }
    }
    int f = lane & 15;
    int cg = bcol + wx * 64 + f;
    float bi = bias_p[cg], bff = bias_p[cg + 16], bg = bias_p[cg + 32], bo = bias_p[cg + 48];
    int feat = (blockIdx.y * 2 + wx) * 16 + f;
#pragma unroll
    for (int mm = 0; mm < 2; ++mm)
#pragma unroll
        for (int j = 0; j < 4; ++j) {
            int row = brow + wy * 32 + mm * 16 + (lane >> 4) * 4 + j;
            float gi = fsigm(acc[mm][0][j] + bi);
            float gf = fsigm(acc[mm][1][j] + bff);
            float gg = ftanh(acc[mm][2][j] + bg);
            float go = fsigm(acc[mm][3][j] + bo);
            size_t idx = (size_t)row * HDIM + feat;
            float cn_ = gf * c[idx] + gi * gg;
            c[idx] = cn_;
            float h = go * ftanh(cn_);
            unsigned short hb = f2bf(h);
            if (PHASE == 0) {
                xa[(size_t)row * 768 + 512 + feat] = hb;   // h0 -> next-step xb0
                xb[(size_t)row * 512 + feat] = hb;          // h0 -> this-step xb1 input
            } else {
                qout[idx] = h;                              // q = h1 (f32, for attention)
                xa[(size_t)row * 768 + feat] = hb;          // q -> next-step xb0
                xb[(size_t)row * 512 + 256 + feat] = hb;    // h1 -> next-step xb1
            }
        }
}

extern "C" void kernel_launch(void* const* d_in, const int* in_sizes, int n_in,
                              void* d_out, int out_size, void* d_ws, size_t ws_size,
                              hipStream_t stream) {
    const float* nodes = (const float*)d_in[0];
    const int* gid = (const int*)d_in[1];
    const float* Wih0 = (const float*)d_in[3];
    const float* Whh0 = (const float*)d_in[4];
    const float* bih0 = (const float*)d_in[5];
    const float* bhh0 = (const float*)d_in[6];
    const float* Wih1 = (const float*)d_in[7];
    const float* Whh1 = (const float*)d_in[8];
    const float* bih1 = (const float*)d_in[9];
    const float* bhh1 = (const float*)d_in[10];
    int N = in_sizes[0] / HDIM;
    int B = out_size / (2 * HDIM);
    float* out = (float*)d_out;

    const size_t AL = 512;
    auto rnd = [&](size_t b) { return (b + AL - 1) & ~(AL - 1); };
    size_t offs_b  = rnd((size_t)(B + 1) * 4);
    size_t q_b     = rnd((size_t)B * HDIM * 4);
    size_t xb0_b   = rnd((size_t)B * 768 * 2);
    size_t xb1_b   = rnd((size_t)B * 512 * 2);
    size_t w0_b    = rnd((size_t)1024 * 768 * 2);
    size_t w1_b    = rnd((size_t)1024 * 512 * 2);
    size_t bias_b  = rnd((size_t)1024 * 4);
    size_t nb_b    = rnd((size_t)N * HDIM * 2);
    size_t base_need = offs_b + 3 * q_b + 2 * xb0_b + 2 * xb1_b + w0_b + w1_b + 2 * bias_b;
    bool useBF = (base_need + nb_b <= ws_size);

    char* w = (char*)d_ws;
    unsigned short* nodes_bf = nullptr;
    if (useBF) { nodes_bf = (unsigned short*)w; w += nb_b; }
    int* offs = (int*)w;               w += offs_b;
    float* q  = (float*)w;             w += q_b;
    float* c0 = (float*)w;             w += q_b;
    float* c1 = (float*)w;             w += q_b;
    unsigned short* xb0v[2]; unsigned short* xb1v[2];
    xb0v[0] = (unsigned short*)w;      w += xb0_b;
    xb0v[1] = (unsigned short*)w;      w += xb0_b;
    xb1v[0] = (unsigned short*)w;      w += xb1_b;
    xb1v[1] = (unsigned short*)w;      w += xb1_b;
    unsigned short* W0 = (unsigned short*)w;  w += w0_b;
    unsigned short* W1 = (unsigned short*)w;  w += w1_b;
    float* b0 = (float*)w;             w += bias_b;
    float* b1 = (float*)w;             w += bias_b;

    {
        int prep_total = 1024 * 768 + 1024 * 512 + 1024 + B + 1;
        int prep_blocks = (prep_total + 255) / 256;
        dim3 grid(B + prep_blocks);
        if (useBF)
            k_prep_mean<true><<<grid, dim3(256), 0, stream>>>(
                nodes, gid, Wih0, Whh0, bih0, bhh0, Wih1, Whh1, bih1, bhh1,
                W0, W1, b0, b1, offs, nodes_bf, xb0v[0], xb1v[0], c0, c1, N, B);
        else
            k_prep_mean<false><<<grid, dim3(256), 0, stream>>>(
                nodes, gid, Wih0, Whh0, bih0, bhh0, Wih1, Whh1, bih1, bhh1,
                W0, W1, b0, b1, offs, nullptr, xb0v[0], xb1v[0], c0, c1, N, B);
    }

    for (int s = 0; s < 5; ++s) {
        int vr = s & 1, vw = vr ^ 1;
        k_gemm_lstm<768, 0><<<dim3(B / 64, 8), dim3(256), 0, stream>>>(
            xb0v[vr], W0, b0, c0, xb0v[vw], xb1v[vr], nullptr);
        k_gemm_lstm<512, 1><<<dim3(B / 64, 8), dim3(256), 0, stream>>>(
            xb1v[vr], W1, b1, c1, xb0v[vw], xb1v[vw], q);
        if (s < 4) {
            if (useBF)
                k_attn<false><<<dim3(B), dim3(256), 0, stream>>>(nodes_bf, offs, q, nullptr, xb0v[vw], N);
            else
                k_attn_f32<false><<<dim3(B), dim3(256), 0, stream>>>(nodes, offs, q, nullptr, xb0v[vw]);
        } else {
            if (useBF)
                k_attn<true><<<dim3(B), dim3(256), 0, stream>>>(nodes_bf, offs, q, out, nullptr, N);
            else
                k_attn_f32<true><<<dim3(B), dim3(256), 0, stream>>>(nodes, offs, q, out, nullptr);
        }
    }
}

// Round 13
// 260.713 us; speedup vs baseline: 1.0442x; 1.0442x over previous
//
#include <hip/hip_runtime.h>
#include <hip/hip_bf16.h>
#include <cstdint>

#define HDIM 256

typedef __attribute__((ext_vector_type(8))) short bf16x8;
typedef __attribute__((ext_vector_type(4))) float f32x4;

__device__ __forceinline__ float bf2f(unsigned short u) {
    union { unsigned u; float f; } v; v.u = ((unsigned)u) << 16; return v.f;
}
__device__ __forceinline__ unsigned short f2bf(float f) {
    union { float f; unsigned u; } v; v.f = f;
    unsigned u = v.u;
    return (unsigned short)((u + 0x7fffu + ((u >> 16) & 1u)) >> 16);
}
__device__ __forceinline__ void gload_lds16(const void* g, void* l) {
    __builtin_amdgcn_global_load_lds((const __attribute__((address_space(1))) void*)g,
                                     (__attribute__((address_space(3))) void*)l, 16, 0, 0);
}
__device__ __forceinline__ float fsigm(float x) {
    return 1.f / (1.f + __expf(-x));
}
__device__ __forceinline__ float ftanh(float x) {
    float ax = fabsf(x);
    float z = __expf(2.f * ax);
    float th = 1.f - 2.f / (z + 1.f);
    return copysignf(th, x);
}

// ---- merged: iteration-0 mean/cast (blocks [0,B)) + weight/bias/offs prep (tail) ----
// mean blocks: per-graph column mean (q=0 -> uniform softmax), f32->bf16 cast
//              (non-temporal f32 reads; REGULAR bf16 stores — R12 proved nt-stores
//              cost ~11us by making attn pass 1 L3-cold), zero-init of LSTM state.
// prep blocks: gate-interleaved weight permute + bias + segment offsets.
// permuted row r -> gate g=(r>>4)&3, feat=((r>>6)<<4)|(r&15), orig row = g*256+feat
template<bool BF>
__global__ void __launch_bounds__(256) k_prep_mean(
        const float* __restrict__ nodes, const int* __restrict__ gid,
        const float* __restrict__ Wih0, const float* __restrict__ Whh0,
        const float* __restrict__ bih0, const float* __restrict__ bhh0,
        const float* __restrict__ Wih1, const float* __restrict__ Whh1,
        const float* __restrict__ bih1, const float* __restrict__ bhh1,
        unsigned short* __restrict__ W0, unsigned short* __restrict__ W1,
        float* __restrict__ b0, float* __restrict__ b1,
        int* __restrict__ offs,
        unsigned short* __restrict__ nbf, unsigned short* __restrict__ xr,
        unsigned short* __restrict__ xb1z,
        float* __restrict__ c0, float* __restrict__ c1, int N, int B) {
    int bid = blockIdx.x;
    int t = threadIdx.x;
    if (bid < B) {
        __shared__ float red[4 * HDIM];
        int g = bid;
        int lane = t & 63, wid = t >> 6;
        int lo = 0, hi = N;
        while (lo < hi) { int mid = (lo + hi) >> 1; if (gid[mid] < g) lo = mid + 1; else hi = mid; }
        int start = lo;
        hi = N;
        while (lo < hi) { int mid = (lo + hi) >> 1; if (gid[mid] < g + 1) lo = mid + 1; else hi = mid; }
        int end = lo;
        int Nm1 = N - 1;
        size_t col = (size_t)lane * 4;
        f32x4 acc = {0.f, 0.f, 0.f, 0.f};
        for (int vi0 = start + wid * 4; vi0 < end; vi0 += 16) {
            f32x4 v[4];
#pragma unroll
            for (int r = 0; r < 4; ++r)
                v[r] = __builtin_nontemporal_load(
                    (const f32x4*)(nodes + (size_t)min(vi0 + r, Nm1) * HDIM + col));
#pragma unroll
            for (int r = 0; r < 4; ++r) {
                if (vi0 + r < end) {      // wave-uniform
                    acc += v[r];
                    if (BF) {
                        ushort4 o; o.x = f2bf(v[r].x); o.y = f2bf(v[r].y);
                        o.z = f2bf(v[r].z); o.w = f2bf(v[r].w);
                        *(ushort4*)(nbf + (size_t)(vi0 + r) * HDIM + col) = o;
                    }
                }
            }
        }
        *(f32x4*)(red + wid * HDIM + lane * 4) = acc;
        __syncthreads();
        int n = end - start;
        float r = red[t] + red[HDIM + t] + red[2 * HDIM + t] + red[3 * HDIM + t];
        r = (n > 0) ? r / (float)n : 0.f;
        xr[(size_t)g * 768 + t] = 0;                 // q block of step-0 xb0
        xr[(size_t)g * 768 + HDIM + t] = f2bf(r);    // r block
        xr[(size_t)g * 768 + 512 + t] = 0;           // h0 block
        xb1z[(size_t)g * 512 + 256 + t] = 0;         // h1prev block of step-0 xb1
        c0[(size_t)g * HDIM + t] = 0.f;
        c1[(size_t)g * HDIM + t] = 0.f;
        return;
    }
    int idx = (bid - B) * 256 + t;
    const int n0 = 1024 * 768, n1 = 1024 * 512;
    if (idx < n0) {
        int r = idx / 768, k = idx - r * 768;
        int orow = ((r >> 4) & 3) * 256 + ((r >> 6) << 4) + (r & 15);
        float v = (k < 512) ? Wih0[orow * 512 + k] : Whh0[orow * 256 + (k - 512)];
        W0[idx] = f2bf(v);
    } else if (idx < n0 + n1) {
        int j = idx - n0;
        int r = j >> 9, k = j & 511;
        int orow = ((r >> 4) & 3) * 256 + ((r >> 6) << 4) + (r & 15);
        float v = (k < 256) ? Wih1[orow * 256 + k] : Whh1[orow * 256 + (k - 256)];
        W1[j] = f2bf(v);
    } else if (idx < n0 + n1 + 1024) {
        int r = idx - (n0 + n1);
        int orow = ((r >> 4) & 3) * 256 + ((r >> 6) << 4) + (r & 15);
        b0[r] = bih0[orow] + bhh0[orow];
        b1[r] = bih1[orow] + bhh1[orow];
    } else if (idx <= n0 + n1 + 1024 + B) {
        int g = idx - (n0 + n1 + 1024);
        int lo = 0, hi = N;
        while (lo < hi) { int mid = (lo + hi) >> 1; if (gid[mid] < g) lo = mid + 1; else hi = mid; }
        offs[g] = lo;
    }
}

// ---- attention: single global read, register-online softmax, 2-deep prefetch ----
// wave handles 4 nodes/iter: half h -> rows vi0+h and vi0+2+h
template<bool LAST>
__global__ void __launch_bounds__(256) k_attn(const unsigned short* __restrict__ nb,
                                              const int* __restrict__ offs,
                                              const float* __restrict__ q,
                                              float* __restrict__ out,
                                              unsigned short* __restrict__ xr, int N) {
    __shared__ float qs[HDIM];
    __shared__ float redr[8 * HDIM];
    __shared__ float redm[8], redd[8];
    int g = blockIdx.x, t = threadIdx.x;
    int lane = t & 63, wid = t >> 6;
    int half = lane >> 5, hl = lane & 31;
    int start = offs[g], end = offs[g + 1];
    int Nm1 = N - 1;
    float qv = q[(size_t)g * HDIM + t];
    qs[t] = qv;
    __syncthreads();
    float qv8[8];
#pragma unroll
    for (int j = 0; j < 8; ++j) qv8[j] = qs[hl * 8 + j];
    float m = -INFINITY, d = 0.f, racc[8];
#pragma unroll
    for (int j = 0; j < 8; ++j) racc[j] = 0.f;
    size_t col = (size_t)hl * 8;
    int vi0 = start + wid * 4;
    bf16x8 cura = *(const bf16x8*)(nb + (size_t)min(vi0 + half, Nm1) * HDIM + col);
    bf16x8 curb = *(const bf16x8*)(nb + (size_t)min(vi0 + 2 + half, Nm1) * HDIM + col);
    for (; vi0 < end; vi0 += 16) {
        int nvi = vi0 + 16;
        bf16x8 nxta = *(const bf16x8*)(nb + (size_t)min(nvi + half, Nm1) * HDIM + col);
        bf16x8 nxtb = *(const bf16x8*)(nb + (size_t)min(nvi + 2 + half, Nm1) * HDIM + col);
        int a = vi0 + half, b = a + 2;
        if (a < end) {                 // uniform per 32-lane half
            float xa[8], xb[8];
#pragma unroll
            for (int j = 0; j < 8; ++j) {
                xa[j] = bf2f((unsigned short)cura[j]);
                xb[j] = bf2f((unsigned short)curb[j]);
            }
            float ea = 0.f, eb = 0.f;
#pragma unroll
            for (int j = 0; j < 8; ++j) {
                ea = fmaf(qv8[j], xa[j], ea);
                eb = fmaf(qv8[j], xb[j], eb);
            }
#pragma unroll
            for (int o = 16; o >= 1; o >>= 1) {
                ea += __shfl_xor(ea, o, 64);
                eb += __shfl_xor(eb, o, 64);
            }
            if (b >= end) eb = -INFINITY;
            float nm = fmaxf(fmaxf(m, ea), eb);
            float sc = __expf(m - nm);
            float wa = __expf(ea - nm);
            float wb = __expf(eb - nm);
            m = nm;
            d = fmaf(d, sc, wa + wb);
#pragma unroll
            for (int j = 0; j < 8; ++j)
                racc[j] = fmaf(racc[j], sc, fmaf(wa, xa[j], wb * xb[j]));
        }
        cura = nxta; curb = nxtb;
    }
    int g2 = wid * 2 + half;
    *(float4*)(redr + g2 * HDIM + hl * 8)     = (float4){racc[0], racc[1], racc[2], racc[3]};
    *(float4*)(redr + g2 * HDIM + hl * 8 + 4) = (float4){racc[4], racc[5], racc[6], racc[7]};
    if (hl == 0) { redm[g2] = m; redd[g2] = d; }
    __syncthreads();
    float M = -INFINITY;
#pragma unroll
    for (int i = 0; i < 8; ++i) M = fmaxf(M, redm[i]);
    float D = 0.f, R = 0.f;
#pragma unroll
    for (int i = 0; i < 8; ++i) {
        float s = (redm[i] == -INFINITY) ? 0.f : __expf(redm[i] - M);
        D += redd[i] * s;
        R += redr[i * HDIM + t] * s;
    }
    float r = (D > 0.f) ? R / D : 0.f;
    if (LAST) {
        size_t ob = (size_t)g * (2 * HDIM);
        out[ob + t] = qv;
        out[ob + HDIM + t] = r;
    } else {
        xr[(size_t)g * 768 + HDIM + t] = f2bf(r);
    }
}

// ---- f32 fallback attention (no bf16 workspace) ----
template<bool LAST>
__global__ void __launch_bounds__(256) k_attn_f32(const float* __restrict__ nf,
                                                  const int* __restrict__ offs,
                                                  const float* __restrict__ q,
                                                  float* __restrict__ out,
                                                  unsigned short* __restrict__ xr) {
    __shared__ float qs[HDIM];
    __shared__ float redr[4 * HDIM];
    __shared__ float redm[4], redd[4];
    int g = blockIdx.x, t = threadIdx.x;
    int lane = t & 63, wid = t >> 6;
    int start = offs[g], end = offs[g + 1];
    float qv = q[(size_t)g * HDIM + t];
    qs[t] = qv;
    __syncthreads();
    float4 qq = *(const float4*)(qs + lane * 4);
    float m = -INFINITY, d = 0.f;
    float4 racc = {0.f, 0.f, 0.f, 0.f};
    for (int vi = start + wid; vi < end; vi += 4) {
        float4 x = *(const float4*)(nf + (size_t)vi * HDIM + lane * 4);
        float e = qq.x * x.x + qq.y * x.y + qq.z * x.z + qq.w * x.w;
#pragma unroll
        for (int o = 32; o >= 1; o >>= 1) e += __shfl_xor(e, o, 64);
        float nm = fmaxf(m, e);
        float sc = __expf(m - nm);
        float wv = __expf(e - nm);
        m = nm;
        d = d * sc + wv;
        racc.x = racc.x * sc + wv * x.x;
        racc.y = racc.y * sc + wv * x.y;
        racc.z = racc.z * sc + wv * x.z;
        racc.w = racc.w * sc + wv * x.w;
    }
    *(float4*)(redr + wid * HDIM + lane * 4) = racc;
    if (lane == 0) { redm[wid] = m; redd[wid] = d; }
    __syncthreads();
    float M = fmaxf(fmaxf(redm[0], redm[1]), fmaxf(redm[2], redm[3]));
    float D = 0.f, R = 0.f;
#pragma unroll
    for (int i = 0; i < 4; ++i) {
        float s = (redm[i] == -INFINITY) ? 0.f : __expf(redm[i] - M);
        D += redd[i] * s;
        R += redr[i * HDIM + t] * s;
    }
    float r = (D > 0.f) ? R / D : 0.f;
    if (LAST) {
        size_t ob = (size_t)g * (2 * HDIM);
        out[ob + t] = qv;
        out[ob + HDIM + t] = r;
    } else {
        xr[(size_t)g * 768 + HDIM + t] = f2bf(r);
    }
}

// ---- bf16 MFMA GEMM (64x128 tile, 4 waves), BK=64, 3-buffer pipelined LDS
//      (prefetch distance 2, counted vmcnt, raw barriers), XOR chunk swizzle,
//      fused LSTM-cell epilogue. Gate-interleaved W layout (see k_prep_mean). ----
template<int K, int PHASE>
__global__ void __launch_bounds__(256) k_gemm_lstm(const unsigned short* __restrict__ A,
                                                   const unsigned short* __restrict__ W,
                                                   const float* __restrict__ bias_p,
                                                   float* __restrict__ c,
                                                   unsigned short* __restrict__ xa,
                                                   unsigned short* __restrict__ xb,
                                                   float* __restrict__ qout) {
    constexpr int BK = 64;
    constexpr int NT = K / BK;           // 12 (K=768) or 8 (K=512)
    __shared__ unsigned short lA[3 * 64 * BK];    // 24 KB
    __shared__ unsigned short lB[3 * 128 * BK];   // 48 KB
    int t = threadIdx.x, lane = t & 63, wid = t >> 6;
    int wy = wid >> 1, wx = wid & 1;
    int brow = blockIdx.x * 64, bcol = blockIdx.y * 128;
    f32x4 acc[2][4];
#pragma unroll
    for (int i = 0; i < 2; ++i)
#pragma unroll
        for (int j = 0; j < 4; ++j) acc[i][j] = (f32x4){0.f, 0.f, 0.f, 0.f};
    const unsigned short* gA = A + (size_t)brow * K;
    const unsigned short* gW = W + (size_t)bcol * K;
    auto stage = [&](int tt, int b) {
        int k0 = tt * BK;
        unsigned short* dA = lA + b * (64 * BK);
        unsigned short* dB = lB + b * (128 * BK);
#pragma unroll
        for (int r = 0; r < 2; ++r) {
            int u = t + r * 256;
            int row = u >> 3, sc8 = (u & 7) ^ (row & 7);
            gload_lds16(gA + (size_t)row * K + k0 + sc8 * 8, dA + u * 8);
        }
#pragma unroll
        for (int r = 0; r < 4; ++r) {
            int u = t + r * 256;
            int row = u >> 3, sc8 = (u & 7) ^ (row & 7);
            gload_lds16(gW + (size_t)row * K + k0 + sc8 * 8, dB + u * 8);
        }
    };
    stage(0, 0);
    stage(1, 1);
    asm volatile("s_waitcnt vmcnt(6)" ::: "memory");   // tile 0 landed (own wave)
    __builtin_amdgcn_s_barrier();                       // -> landed for all waves
    int arow = wy * 32 + (lane & 15);
    int brow2 = wx * 64 + (lane & 15);
    int gc8 = lane >> 4;                                // col-chunk base (kh adds 4)
#pragma unroll
    for (int tt = 0; tt < NT; ++tt) {
        const unsigned short* bA = lA + (tt % 3) * (64 * BK);
        const unsigned short* bB = lB + (tt % 3) * (128 * BK);
        bf16x8 af[2][2], bfr[2][4];
#pragma unroll
        for (int kh = 0; kh < 2; ++kh) {
#pragma unroll
            for (int mm = 0; mm < 2; ++mm) {
                int row = arow + mm * 16;
                int ch = (gc8 + kh * 4) ^ (row & 7);
                af[kh][mm] = *(const bf16x8*)(bA + row * BK + ch * 8);
            }
#pragma unroll
            for (int nn = 0; nn < 4; ++nn) {
                int row = brow2 + nn * 16;
                int ch = (gc8 + kh * 4) ^ (row & 7);
                bfr[kh][nn] = *(const bf16x8*)(bB + row * BK + ch * 8);
            }
        }
        if (tt + 2 < NT) stage(tt + 2, (tt + 2) % 3);   // flies under MFMA + next stall
#pragma unroll
        for (int kh = 0; kh < 2; ++kh)
#pragma unroll
            for (int mm = 0; mm < 2; ++mm)
#pragma unroll
                for (int nn = 0; nn < 4; ++nn)
                    acc[mm][nn] = __builtin_amdgcn_mfma_f32_16x16x32_bf16(
                        af[kh][mm], bfr[kh][nn], acc[mm][nn], 0, 0, 0);
        if (tt + 1 < NT) {
            if (tt + 2 < NT) asm volatile("s_waitcnt vmcnt(6)" ::: "memory");
            else             asm volatile("s_waitcnt vmcnt(0)" ::: "memory");
            __builtin_amdgcn_s_barrier();
        }
    }
    int f = lane & 15;
    int cg = bcol + wx * 64 + f;
    float bi = bias_p[cg], bff = bias_p[cg + 16], bg = bias_p[cg + 32], bo = bias_p[cg + 48];
    int feat = (blockIdx.y * 2 + wx) * 16 + f;
#pragma unroll
    for (int mm = 0; mm < 2; ++mm)
#pragma unroll
        for (int j = 0; j < 4; ++j) {
            int row = brow + wy * 32 + mm * 16 + (lane >> 4) * 4 + j;
            float gi = fsigm(acc[mm][0][j] + bi);
            float gf = fsigm(acc[mm][1][j] + bff);
            float gg = ftanh(acc[mm][2][j] + bg);
            float go = fsigm(acc[mm][3][j] + bo);
            size_t idx = (size_t)row * HDIM + feat;
            float cn_ = gf * c[idx] + gi * gg;
            c[idx] = cn_;
            float h = go * ftanh(cn_);
            unsigned short hb = f2bf(h);
            if (PHASE == 0) {
                xa[(size_t)row * 768 + 512 + feat] = hb;   // h0 -> next-step xb0
                xb[(size_t)row * 512 + feat] = hb;          // h0 -> this-step xb1 input
            } else {
                qout[idx] = h;                              // q = h1 (f32, for attention)
                xa[(size_t)row * 768 + feat] = hb;          // q -> next-step xb0
                xb[(size_t)row * 512 + 256 + feat] = hb;    // h1 -> next-step xb1
            }
        }
}

extern "C" void kernel_launch(void* const* d_in, const int* in_sizes, int n_in,
                              void* d_out, int out_size, void* d_ws, size_t ws_size,
                              hipStream_t stream) {
    const float* nodes = (const float*)d_in[0];
    const int* gid = (const int*)d_in[1];
    const float* Wih0 = (const float*)d_in[3];
    const float* Whh0 = (const float*)d_in[4];
    const float* bih0 = (const float*)d_in[5];
    const float* bhh0 = (const float*)d_in[6];
    const float* Wih1 = (const float*)d_in[7];
    const float* Whh1 = (const float*)d_in[8];
    const float* bih1 = (const float*)d_in[9];
    const float* bhh1 = (const float*)d_in[10];
    int N = in_sizes[0] / HDIM;
    int B = out_size / (2 * HDIM);
    float* out = (float*)d_out;

    const size_t AL = 512;
    auto rnd = [&](size_t b) { return (b + AL - 1) & ~(AL - 1); };
    size_t offs_b  = rnd((size_t)(B + 1) * 4);
    size_t q_b     = rnd((size_t)B * HDIM * 4);
    size_t xb0_b   = rnd((size_t)B * 768 * 2);
    size_t xb1_b   = rnd((size_t)B * 512 * 2);
    size_t w0_b    = rnd((size_t)1024 * 768 * 2);
    size_t w1_b    = rnd((size_t)1024 * 512 * 2);
    size_t bias_b  = rnd((size_t)1024 * 4);
    size_t nb_b    = rnd((size_t)N * HDIM * 2);
    size_t base_need = offs_b + 3 * q_b + 2 * xb0_b + 2 * xb1_b + w0_b + w1_b + 2 * bias_b;
    bool useBF = (base_need + nb_b <= ws_size);

    char* w = (char*)d_ws;
    unsigned short* nodes_bf = nullptr;
    if (useBF) { nodes_bf = (unsigned short*)w; w += nb_b; }
    int* offs = (int*)w;               w += offs_b;
    float* q  = (float*)w;             w += q_b;
    float* c0 = (float*)w;             w += q_b;
    float* c1 = (float*)w;             w += q_b;
    unsigned short* xb0v[2]; unsigned short* xb1v[2];
    xb0v[0] = (unsigned short*)w;      w += xb0_b;
    xb0v[1] = (unsigned short*)w;      w += xb0_b;
    xb1v[0] = (unsigned short*)w;      w += xb1_b;
    xb1v[1] = (unsigned short*)w;      w += xb1_b;
    unsigned short* W0 = (unsigned short*)w;  w += w0_b;
    unsigned short* W1 = (unsigned short*)w;  w += w1_b;
    float* b0 = (float*)w;             w += bias_b;
    float* b1 = (float*)w;             w += bias_b;

    {
        int prep_total = 1024 * 768 + 1024 * 512 + 1024 + B + 1;
        int prep_blocks = (prep_total + 255) / 256;
        dim3 grid(B + prep_blocks);
        if (useBF)
            k_prep_mean<true><<<grid, dim3(256), 0, stream>>>(
                nodes, gid, Wih0, Whh0, bih0, bhh0, Wih1, Whh1, bih1, bhh1,
                W0, W1, b0, b1, offs, nodes_bf, xb0v[0], xb1v[0], c0, c1, N, B);
        else
            k_prep_mean<false><<<grid, dim3(256), 0, stream>>>(
                nodes, gid, Wih0, Whh0, bih0, bhh0, Wih1, Whh1, bih1, bhh1,
                W0, W1, b0, b1, offs, nullptr, xb0v[0], xb1v[0], c0, c1, N, B);
    }

    for (int s = 0; s < 5; ++s) {
        int vr = s & 1, vw = vr ^ 1;
        k_gemm_lstm<768, 0><<<dim3(B / 64, 8), dim3(256), 0, stream>>>(
            xb0v[vr], W0, b0, c0, xb0v[vw], xb1v[vr], nullptr);
        k_gemm_lstm<512, 1><<<dim3(B / 64, 8), dim3(256), 0, stream>>>(
            xb1v[vr], W1, b1, c1, xb0v[vw], xb1v[vw], q);
        if (s < 4) {
            if (useBF)
                k_attn<false><<<dim3(B), dim3(256), 0, stream>>>(nodes_bf, offs, q, nullptr, xb0v[vw], N);
            else
                k_attn_f32<false><<<dim3(B), dim3(256), 0, stream>>>(nodes, offs, q, nullptr, xb0v[vw]);
        } else {
            if (useBF)
                k_attn<true><<<dim3(B), dim3(256), 0, stream>>>(nodes_bf, offs, q, out, nullptr, N);
            else
                k_attn_f32<true><<<dim3(B), dim3(256), 0, stream>>>(nodes, offs, q, out, nullptr);
        }
    }
}